// Round 9
// baseline (162.591 us; speedup 1.0000x reference)
//
#include <hip/hip_runtime.h>
#include <hip/hip_bf16.h>
#include <math.h>

// ---------------------------------------------------------------------------
// Workspace layout (float offsets).
// A3 (stage-3 output) aliases OUT1: OUT1 is dead once stage2 completes.
// ---------------------------------------------------------------------------
constexpr size_t OFF_OUT1 = 0;                                // [256][6][79][80]
constexpr size_t OFF_OUT2 = (size_t)256 * 6 * 79 * 80;        // [256][12][38][40]
constexpr size_t OFF_A3   = OFF_OUT1;                         // [256][18][18][18]

// ---------------------------------------------------------------------------
// Fused conv3x3(VALID)+bias+quant_relu+maxpool2 (stages 1-2), direct-global
// reads with 3-deep prefetch ring + in-kernel weight self-quantization.
// (Unchanged from R8 — verified at ~65 us combined.)
// ---------------------------------------------------------------------------
template<int CIN, int COUT, int NCO, int HIN, int WSIN,
         int HPOOL, int WPOOL, int WSOUT, int XG, int RB,
         int THREADS, bool HAS_BIAS>
__global__ __launch_bounds__(THREADS)
void conv_stage(const float* __restrict__ in,
                const float* __restrict__ w_raw,
                const float* __restrict__ b_raw,
                const float* __restrict__ s_prev,
                const float* __restrict__ s_act,
                float* __restrict__ out)
{
    constexpr int GROUPS = COUT / NCO;
    constexpr int W4IN   = WSIN / 4;
    constexpr int NW     = COUT * CIN * 9;
    constexpr int STEPS  = 4 * CIN;
    static_assert(NCO * GROUPS == COUT, "NCO divides COUT");
    static_assert(GROUPS * XG * RB <= THREADS, "single compute pass");
    static_assert(4 * XG == WSOUT, "full padded row coverage");
    static_assert(WSIN % 4 == 0, "vec4 loads");

    __shared__ float lw[NW];
    __shared__ float lb[COUT];
    __shared__ float red[THREADS];

    const int r0  = blockIdx.x * RB;
    const int n   = blockIdx.y;
    const int tid = threadIdx.x;

    float mx = 0.0f;
    for (int i = tid; i < NW; i += THREADS) {
        const float v = w_raw[i];
        lw[i] = v;
        mx = fmaxf(mx, fabsf(v));
    }
    if (HAS_BIAS)
        for (int i = tid; i < COUT; i += THREADS) lb[i] = b_raw[i];
    red[tid] = mx;
    __syncthreads();
    for (int s = THREADS / 2; s > 0; s >>= 1) {
        if (tid < s) red[tid] = fmaxf(red[tid], red[tid + s]);
        __syncthreads();
    }
    const float sw_ = red[0] / 3.0f;
    for (int i = tid; i < NW; i += THREADS) {
        float q = rintf(lw[i] / sw_);
        q = fminf(fmaxf(q, -3.0f), 3.0f);
        lw[i] = q * sw_;
    }
    if (HAS_BIAS) {
        const float sb = sw_ * (s_prev[0] / 15.0f);
        for (int i = tid; i < COUT; i += THREADS)
            lb[i] = rintf(lb[i] / sb) * sb;
    }
    __syncthreads();

    const int o = tid;
    if (o >= GROUPS * XG * RB) return;
    const int cog = o % GROUPS;
    const int xg  = (o / GROUPS) % XG;
    const int ry  = o / (GROUPS * XG);
    const int r   = r0 + ry;
    if (r >= HPOOL) return;

    const float step = s_act[0] / 15.0f;

    const int u0 = 2 * xg;
    const int u1 = 2 * xg + 1;
    const int u2 = (2 * xg + 2 < W4IN) ? (2 * xg + 2) : (W4IN - 1);

    const float* base = in + (size_t)n * CIN * HIN * WSIN + (size_t)(2 * r) * WSIN;

    float acc[NCO][16];
#pragma unroll
    for (int j = 0; j < NCO; ++j)
#pragma unroll
        for (int i = 0; i < 16; ++i) acc[j][i] = 0.0f;

    float4 buf[3][3];
    float  wv[NCO][9];

#define ISSUE_STEP(S)                                                          \
    {                                                                          \
        const float* rp = base + (size_t)((S) >> 2) * HIN * WSIN               \
                               + (size_t)((S) & 3) * WSIN;                     \
        buf[(S) % 3][0] = *(const float4*)&rp[4 * u0];                         \
        buf[(S) % 3][1] = *(const float4*)&rp[4 * u1];                         \
        buf[(S) % 3][2] = *(const float4*)&rp[4 * u2];                         \
    }

    ISSUE_STEP(0);
    ISSUE_STEP(1);

#pragma unroll
    for (int s = 0; s < STEPS; ++s) {
        const int c  = s >> 2;
        const int rr = s & 3;

        if (s + 2 < STEPS) ISSUE_STEP(s + 2);

        if (rr == 0) {
#pragma unroll
            for (int j = 0; j < NCO; ++j)
#pragma unroll
                for (int k = 0; k < 9; ++k)
                    wv[j][k] = lw[((NCO * cog + j) * CIN + c) * 9 + k];
        }

        const float* row = (const float*)buf[s % 3];

        if (rr < 3) {
#pragma unroll
            for (int j = 0; j < NCO; ++j)
#pragma unroll
                for (int kc = 0; kc < 3; ++kc)
#pragma unroll
                    for (int xx = 0; xx < 8; ++xx)
                        acc[j][xx] = fmaf(row[xx + kc], wv[j][rr * 3 + kc], acc[j][xx]);
        }
        if (rr >= 1) {
#pragma unroll
            for (int j = 0; j < NCO; ++j)
#pragma unroll
                for (int kc = 0; kc < 3; ++kc)
#pragma unroll
                    for (int xx = 0; xx < 8; ++xx)
                        acc[j][8 + xx] = fmaf(row[xx + kc], wv[j][(rr - 1) * 3 + kc], acc[j][8 + xx]);
        }
    }
#undef ISSUE_STEP

#pragma unroll
    for (int j = 0; j < NCO; ++j) {
        const int co = NCO * cog + j;
        const float bias = HAS_BIAS ? lb[co] : 0.0f;
        float4 st;
#pragma unroll
        for (int t = 0; t < 4; ++t) {
            float m = fmaxf(fmaxf(acc[j][2 * t], acc[j][2 * t + 1]),
                            fmaxf(acc[j][8 + 2 * t], acc[j][8 + 2 * t + 1]));
            float v = fmaxf(m + bias, 0.0f);
            float q = rintf(v / step);
            q = fminf(fmaxf(q, 0.0f), 15.0f);
            ((float*)&st)[t] = (4 * xg + t < WPOOL) ? q * step : 0.0f;
        }
        *(float4*)&out[(((size_t)n * COUT + co) * HPOOL + r) * WSOUT + 4 * xg] = st;
    }
}

// ---------------------------------------------------------------------------
// Stage 3: [12,38,38]->[18,18,18], one item per thread, input read DIRECTLY
// from global (L2/L3-resident). Grid (2 half-images, 256 images) = 512 blocks
// x 512 threads -> ~4 waves/SIMD. LDS holds only W3 (self-quantized).
// Accumulation order (c, rr, kc) identical to R8 phase 1.
// ---------------------------------------------------------------------------
__global__ __launch_bounds__(512)
void conv3_stage(const float* __restrict__ in2,   // [256][12][38][40]
                 const float* __restrict__ w3, const float* __restrict__ b3,
                 const float* __restrict__ s2, const float* __restrict__ s3,
                 float* __restrict__ a3)          // [256][18][18][18]
{
    __shared__ float lw[1944];
    __shared__ float lb[18];
    __shared__ float red[512];

    const int rb  = blockIdx.x;       // 0..1: rows 9*rb .. 9*rb+8
    const int n   = blockIdx.y;
    const int tid = threadIdx.x;

    float mx = 0.0f;
    for (int i = tid; i < 1944; i += 512) {
        const float v = w3[i];
        lw[i] = v;
        mx = fmaxf(mx, fabsf(v));
    }
    if (tid < 18) lb[tid] = b3[tid];
    red[tid] = mx;
    __syncthreads();
    for (int s = 256; s > 0; s >>= 1) {
        if (tid < s) red[tid] = fmaxf(red[tid], red[tid + s]);
        __syncthreads();
    }
    const float sw = red[0] / 3.0f;
    for (int i = tid; i < 1944; i += 512) {
        float q = rintf(lw[i] / sw);
        q = fminf(fmaxf(q, -3.0f), 3.0f);
        lw[i] = q * sw;
    }
    if (tid < 18) {
        const float sb = sw * (s2[0] / 15.0f);
        lb[tid] = rintf(lb[tid] / sb) * sb;
    }
    __syncthreads();

    if (tid >= 486) return;           // 9 rows x 18 co x 3 thirds
    const int rloc = tid / 54;
    const int rm   = tid - rloc * 54;
    const int co   = rm / 3;
    const int th   = rm - co * 3;     // pooled x in [6*th, 6*th+6)
    const int r    = rb * 9 + rloc;

    const float st = s3[0] / 15.0f;
    const float* base = in2 + (size_t)n * 18240 + (size_t)(2 * r) * 40 + 12 * th;

    float acc0[12], acc1[12];
#pragma unroll
    for (int i = 0; i < 12; ++i) { acc0[i] = 0.f; acc1[i] = 0.f; }

    for (int c = 0; c < 12; ++c) {
        float wv[9];
#pragma unroll
        for (int k = 0; k < 9; ++k) wv[k] = lw[(co * 12 + c) * 9 + k];
        const float* cp = base + (size_t)c * 1520;
#pragma unroll
        for (int rr = 0; rr < 4; ++rr) {
            const float* rp = cp + rr * 40;
            float row[14];
#pragma unroll
            for (int v = 0; v < 7; ++v)
                *(float2*)&row[2 * v] = *(const float2*)&rp[2 * v];
            if (rr < 3) {
#pragma unroll
                for (int kc = 0; kc < 3; ++kc)
#pragma unroll
                    for (int xx = 0; xx < 12; ++xx)
                        acc0[xx] = fmaf(row[xx + kc], wv[rr * 3 + kc], acc0[xx]);
            }
            if (rr >= 1) {
#pragma unroll
                for (int kc = 0; kc < 3; ++kc)
#pragma unroll
                    for (int xx = 0; xx < 12; ++xx)
                        acc1[xx] = fmaf(row[xx + kc], wv[(rr - 1) * 3 + kc], acc1[xx]);
            }
        }
    }

    const float bias = lb[co];
    float* orow = a3 + (size_t)n * 5832 + (size_t)co * 324 + (size_t)r * 18 + 6 * th;
#pragma unroll
    for (int x = 0; x < 6; ++x) {
        float m = fmaxf(fmaxf(acc0[2 * x], acc0[2 * x + 1]),
                        fmaxf(acc1[2 * x], acc1[2 * x + 1]));
        float v = fmaxf(m + bias, 0.0f);
        float q = rintf(v / st);
        q = fminf(fmaxf(q, 0.0f), 15.0f);
        orow[x] = q * st;
    }
}

// ---------------------------------------------------------------------------
// Tail: stage4 + stage5 + fc1 + fc2 + fc3, one block per image.
// LDS: A3 slab (23.3KB, staged coalesced) + W4/W5 + scratch = ~63KB.
// ---------------------------------------------------------------------------
__global__ __launch_bounds__(512)
void tail456(const float* __restrict__ a3in,      // [256][18][18][18]
             const float* __restrict__ w4, const float* __restrict__ b4,
             const float* __restrict__ w5, const float* __restrict__ b5,
             const float* __restrict__ fw1, const float* __restrict__ fb1,
             const float* __restrict__ fw2, const float* __restrict__ fb2,
             const float* __restrict__ fw3,
             const float* __restrict__ s3, const float* __restrict__ s4,
             const float* __restrict__ s5, const float* __restrict__ s6,
             const float* __restrict__ s7,
             float* __restrict__ out)
{
    __shared__ float A3[5832];
    __shared__ float W4q[2916], W5q[2916];
    __shared__ float B4q[18], B5q[18];
    __shared__ float O4[1152];
    __shared__ float A5[162], A6[120], A7[84];
    __shared__ float red[5 * 512];

    const int n   = blockIdx.x;
    const int tid = threadIdx.x;

    // ---- phase 0: stage A3 + weights, compute all max-abs scales ----
    {
        const float4* src = (const float4*)(a3in + (size_t)n * 5832);
        float4* dst = (float4*)A3;
        for (int i = tid; i < 1458; i += 512) dst[i] = src[i];
    }
    float m4 = 0.f, m5 = 0.f, g1 = 0.f, g2 = 0.f, g3 = 0.f;
    for (int i = tid; i < 2916; i += 512) { const float v = w4[i]; W4q[i] = v; m4 = fmaxf(m4, fabsf(v)); }
    for (int i = tid; i < 2916; i += 512) { const float v = w5[i]; W5q[i] = v; m5 = fmaxf(m5, fabsf(v)); }
    {
        const float4* f1 = (const float4*)fw1;   // 4860 float4
        for (int i = tid; i < 4860; i += 512) {
            const float4 v = f1[i];
            g1 = fmaxf(g1, fmaxf(fmaxf(fabsf(v.x), fabsf(v.y)), fmaxf(fabsf(v.z), fabsf(v.w))));
        }
        const float4* f2 = (const float4*)fw2;   // 2520 float4
        for (int i = tid; i < 2520; i += 512) {
            const float4 v = f2[i];
            g2 = fmaxf(g2, fmaxf(fmaxf(fabsf(v.x), fabsf(v.y)), fmaxf(fabsf(v.z), fabsf(v.w))));
        }
        const float4* f3 = (const float4*)fw3;   // 189 float4
        for (int i = tid; i < 189; i += 512) {
            const float4 v = f3[i];
            g3 = fmaxf(g3, fmaxf(fmaxf(fabsf(v.x), fabsf(v.y)), fmaxf(fabsf(v.z), fabsf(v.w))));
        }
    }
    if (tid < 18) { B4q[tid] = b4[tid]; B5q[tid] = b5[tid]; }
    red[tid] = m4; red[512 + tid] = m5; red[1024 + tid] = g1;
    red[1536 + tid] = g2; red[2048 + tid] = g3;
    __syncthreads();
    for (int s = 256; s > 0; s >>= 1) {
        if (tid < s)
#pragma unroll
            for (int j = 0; j < 5; ++j)
                red[j * 512 + tid] = fmaxf(red[j * 512 + tid], red[j * 512 + tid + s]);
        __syncthreads();
    }
    const float sw4 = red[0] / 3.0f, sw5 = red[512] / 3.0f;
    const float sf1 = red[1024] / 3.0f, sf2 = red[1536] / 3.0f, sf3 = red[2048] / 3.0f;

    for (int i = tid; i < 2916; i += 512) { float q = rintf(W4q[i] / sw4); q = fminf(fmaxf(q, -3.f), 3.f); W4q[i] = q * sw4; }
    for (int i = tid; i < 2916; i += 512) { float q = rintf(W5q[i] / sw5); q = fminf(fmaxf(q, -3.f), 3.f); W5q[i] = q * sw5; }
    if (tid < 18) {
        const float sb4 = sw4 * (s3[0] / 15.0f); B4q[tid] = rintf(B4q[tid] / sb4) * sb4;
        const float sb5 = sw5 * (s4[0] / 15.0f); B5q[tid] = rintf(B5q[tid] / sb5) * sb5;
    }
    __syncthreads();

    // ---- stage4: [18,18,18]->[18,8,8] ----
    {
        const float st = s4[0] / 15.0f;
        for (int o = tid; o < 1152; o += 512) {
            const int co = o >> 6;
            const int r  = (o >> 3) & 7;
            const int x  = o & 7;
            float a00 = 0.f, a01 = 0.f, a10 = 0.f, a11 = 0.f;
            for (int c = 0; c < 18; ++c) {
                float win[4][4];
#pragma unroll
                for (int rr = 0; rr < 4; ++rr) {
                    const int base = c * 324 + (2 * r + rr) * 18 + 2 * x;
                    *(float2*)&win[rr][0] = *(const float2*)&A3[base];
                    *(float2*)&win[rr][2] = *(const float2*)&A3[base + 2];
                }
                const float* wp = &W4q[(co * 18 + c) * 9];
#pragma unroll
                for (int kr = 0; kr < 3; ++kr)
#pragma unroll
                    for (int kc = 0; kc < 3; ++kc) {
                        const float wv = wp[kr * 3 + kc];
                        a00 = fmaf(win[kr    ][kc    ], wv, a00);
                        a01 = fmaf(win[kr    ][kc + 1], wv, a01);
                        a10 = fmaf(win[kr + 1][kc    ], wv, a10);
                        a11 = fmaf(win[kr + 1][kc + 1], wv, a11);
                    }
            }
            float m = fmaxf(fmaxf(a00, a01), fmaxf(a10, a11));
            float v = fmaxf(m + B4q[co], 0.0f);
            float q = rintf(v / st);
            q = fminf(fmaxf(q, 0.0f), 15.0f);
            O4[o] = q * st;                  // layout (co, r, x)
        }
    }
    __syncthreads();

    // ---- stage5: [18,8,8]->[18,3,3] = A5[162] ----
    {
        const float st = s5[0] / 15.0f;
        if (tid < 162) {
            const int co  = tid / 9;
            const int rem = tid - co * 9;
            const int r   = rem / 3;
            const int x   = rem - r * 3;
            float a00 = 0.f, a01 = 0.f, a10 = 0.f, a11 = 0.f;
            for (int c = 0; c < 18; ++c) {
                float win[4][4];
#pragma unroll
                for (int rr = 0; rr < 4; ++rr) {
                    const int base = c * 64 + (2 * r + rr) * 8 + 2 * x;
                    *(float2*)&win[rr][0] = *(const float2*)&O4[base];
                    *(float2*)&win[rr][2] = *(const float2*)&O4[base + 2];
                }
                const float* wp = &W5q[(co * 18 + c) * 9];
#pragma unroll
                for (int kr = 0; kr < 3; ++kr)
#pragma unroll
                    for (int kc = 0; kc < 3; ++kc) {
                        const float wv = wp[kr * 3 + kc];
                        a00 = fmaf(win[kr    ][kc    ], wv, a00);
                        a01 = fmaf(win[kr    ][kc + 1], wv, a01);
                        a10 = fmaf(win[kr + 1][kc    ], wv, a10);
                        a11 = fmaf(win[kr + 1][kc + 1], wv, a11);
                    }
            }
            float m = fmaxf(fmaxf(a00, a01), fmaxf(a10, a11));
            float v = fmaxf(m + B5q[co], 0.0f);
            float q = rintf(v / st);
            q = fminf(fmaxf(q, 0.0f), 15.0f);
            A5[tid] = q * st;                // (co, r, x) = reference reshape order
        }
    }
    __syncthreads();

    // ---- fc1: [162]->[120], on-the-fly weight quant ----
    if (tid < 120) {
        float acc = 0.f;
        const float* wr = fw1 + (size_t)tid * 162;
#pragma unroll 6
        for (int k = 0; k < 162; ++k) {
            float q = rintf(wr[k] / sf1);
            q = fminf(fmaxf(q, -3.f), 3.f);
            acc = fmaf(A5[k], q * sf1, acc);
        }
        const float sb = sf1 * (s5[0] / 15.0f);
        acc += rintf(fb1[tid] / sb) * sb;
        const float st = s6[0] / 15.0f;
        float q = rintf(fmaxf(acc, 0.0f) / st);
        q = fminf(fmaxf(q, 0.0f), 15.0f);
        A6[tid] = q * st;
    }
    __syncthreads();

    // ---- fc2: [120]->[84] ----
    if (tid < 84) {
        float acc = 0.f;
        const float* wr = fw2 + (size_t)tid * 120;
#pragma unroll 6
        for (int k = 0; k < 120; ++k) {
            float q = rintf(wr[k] / sf2);
            q = fminf(fmaxf(q, -3.f), 3.f);
            acc = fmaf(A6[k], q * sf2, acc);
        }
        const float sb = sf2 * (s6[0] / 15.0f);
        acc += rintf(fb2[tid] / sb) * sb;
        const float st = s7[0] / 15.0f;
        float q = rintf(fmaxf(acc, 0.0f) / st);
        q = fminf(fmaxf(q, 0.0f), 15.0f);
        A7[tid] = q * st;
    }
    __syncthreads();

    // ---- fc3: [84]->[9] (no bias, no quant) ----
    if (tid < 9) {
        float acc = 0.f;
        const float* wr = fw3 + (size_t)tid * 84;
#pragma unroll 6
        for (int k = 0; k < 84; ++k) {
            float q = rintf(wr[k] / sf3);
            q = fminf(fmaxf(q, -3.f), 3.f);
            acc = fmaf(A7[k], q * sf3, acc);
        }
        out[(size_t)n * 9 + tid] = acc;
    }
}

// ---------------------------------------------------------------------------
extern "C" void kernel_launch(void* const* d_in, const int* in_sizes, int n_in,
                              void* d_out, int out_size, void* d_ws, size_t ws_size,
                              hipStream_t stream)
{
    const float* x   = (const float*)d_in[0];
    const float* w1  = (const float*)d_in[1];
    const float* w2  = (const float*)d_in[2];
    const float* b2  = (const float*)d_in[3];
    const float* w3  = (const float*)d_in[4];
    const float* b3  = (const float*)d_in[5];
    const float* w4  = (const float*)d_in[6];
    const float* b4  = (const float*)d_in[7];
    const float* w5  = (const float*)d_in[8];
    const float* b5  = (const float*)d_in[9];
    const float* fw1 = (const float*)d_in[10];
    const float* fb1 = (const float*)d_in[11];
    const float* fw2 = (const float*)d_in[12];
    const float* fb2 = (const float*)d_in[13];
    const float* fw3 = (const float*)d_in[14];
    const float* s1  = (const float*)d_in[15];
    const float* s2  = (const float*)d_in[16];
    const float* s3  = (const float*)d_in[17];
    const float* s4  = (const float*)d_in[18];
    const float* s5  = (const float*)d_in[19];
    const float* s6  = (const float*)d_in[20];
    const float* s7  = (const float*)d_in[21];

    float* ws = (float*)d_ws;
    float* out = (float*)d_out;

    // stage 1: [256,3,160,160] -> [256,6,79,80p]
    conv_stage<3, 6, 2, 160, 160, 79, 79, 80, 20, 4, 256, false>
        <<<dim3(20, 256), 256, 0, stream>>>(x, w1, nullptr, nullptr, s1, ws + OFF_OUT1);

    // stage 2: -> [256,12,38,40p]
    conv_stage<6, 12, 2, 79, 80, 38, 38, 40, 10, 4, 256, true>
        <<<dim3(10, 256), 256, 0, stream>>>(ws + OFF_OUT1, w2, b2, s1, s2, ws + OFF_OUT2);

    // stage 3: -> [256,18,18,18] (A3, aliases OUT1), 512 blocks x 512 thr
    conv3_stage<<<dim3(2, 256), 512, 0, stream>>>(ws + OFF_OUT2, w3, b3, s2, s3, ws + OFF_A3);

    // stage4 + stage5 + fc1 + fc2 + fc3, one block per image
    tail456<<<256, 512, 0, stream>>>(ws + OFF_A3,
                                     w4, b4, w5, b5,
                                     fw1, fb1, fw2, fb2, fw3,
                                     s3, s4, s5, s6, s7, out);
}

// Round 10
// 138.909 us; speedup vs baseline: 1.1705x; 1.1705x over previous
//
#include <hip/hip_runtime.h>
#include <hip/hip_bf16.h>
#include <math.h>
#include <type_traits>

// ---------------------------------------------------------------------------
// Workspace layout (byte offsets). Intermediates stored as u8 quant levels
// q in [0,15]; the f32 value is reconstructed EXACTLY as (float)q * (s/15)
// (int->f32 exact, single rounding identical to the producer's q*step).
// ---------------------------------------------------------------------------
constexpr size_t OFF_OUT1B = 0;                        // u8 [256][6][79][80]
constexpr size_t OFF_OUT2B = (size_t)256 * 6 * 79 * 80; // u8 [256][12][38][40]

// ---------------------------------------------------------------------------
// Fused conv3x3(VALID)[+bias]+quant_relu+maxpool2 (stages 1-2).
// Direct-global reads, 3-deep prefetch ring, in-kernel weight self-quant.
// IN_U8: input is u8 levels, dequantized with step_in = s_prev/15 (exact).
// Output: u8 levels, 4 packed per dword store.
// ---------------------------------------------------------------------------
template<int CIN, int COUT, int NCO, int HIN, int WSIN,
         int HPOOL, int WPOOL, int WSOUT, int XG, int RB,
         int THREADS, bool HAS_BIAS, bool IN_U8>
__global__ __launch_bounds__(THREADS)
void conv_stage(const void* __restrict__ in_,
                const float* __restrict__ w_raw,
                const float* __restrict__ b_raw,
                const float* __restrict__ s_prev,   // bias scale + input dequant
                const float* __restrict__ s_act,
                unsigned char* __restrict__ out)
{
    using TIN = typename std::conditional<IN_U8, unsigned char, float>::type;
    constexpr int GROUPS = COUT / NCO;
    constexpr int W4IN   = WSIN / 4;     // 4-element units per input row
    constexpr int NW     = COUT * CIN * 9;
    constexpr int STEPS  = 4 * CIN;
    static_assert(NCO * GROUPS == COUT, "NCO divides COUT");
    static_assert(GROUPS * XG * RB <= THREADS, "single compute pass");
    static_assert(4 * XG == WSOUT, "full padded row coverage");
    static_assert(WSIN % 4 == 0, "vec4 loads");

    __shared__ float lw[NW];
    __shared__ float lb[COUT];
    __shared__ float red[THREADS];

    const int r0  = blockIdx.x * RB;
    const int n   = blockIdx.y;
    const int tid = threadIdx.x;

    // ---- weight self-quant (exact, order-independent max) ----
    float mx = 0.0f;
    for (int i = tid; i < NW; i += THREADS) {
        const float v = w_raw[i];
        lw[i] = v;
        mx = fmaxf(mx, fabsf(v));
    }
    if (HAS_BIAS)
        for (int i = tid; i < COUT; i += THREADS) lb[i] = b_raw[i];
    red[tid] = mx;
    __syncthreads();
    for (int s = THREADS / 2; s > 0; s >>= 1) {
        if (tid < s) red[tid] = fmaxf(red[tid], red[tid + s]);
        __syncthreads();
    }
    const float sw_ = red[0] / 3.0f;
    for (int i = tid; i < NW; i += THREADS) {
        float q = rintf(lw[i] / sw_);
        q = fminf(fmaxf(q, -3.0f), 3.0f);
        lw[i] = q * sw_;
    }
    if (HAS_BIAS) {
        const float sb = sw_ * (s_prev[0] / 15.0f);
        for (int i = tid; i < COUT; i += THREADS)
            lb[i] = rintf(lb[i] / sb) * sb;
    }
    __syncthreads();

    const int o = tid;
    if (o >= GROUPS * XG * RB) return;
    const int cog = o % GROUPS;
    const int xg  = (o / GROUPS) % XG;
    const int ry  = o / (GROUPS * XG);
    const int r   = r0 + ry;
    if (r >= HPOOL) return;

    const float step = s_act[0] / 15.0f;
    float step_in = 0.0f;
    if constexpr (IN_U8) step_in = s_prev[0] / 15.0f;

    const int u0 = 2 * xg;
    const int u1 = 2 * xg + 1;
    const int u2 = (2 * xg + 2 < W4IN) ? (2 * xg + 2) : (W4IN - 1);

    const TIN* in   = (const TIN*)in_;
    const TIN* base = in + (size_t)n * CIN * HIN * WSIN + (size_t)(2 * r) * WSIN;

    float acc[NCO][16];
#pragma unroll
    for (int j = 0; j < NCO; ++j)
#pragma unroll
        for (int i = 0; i < 16; ++i) acc[j][i] = 0.0f;

    float4       fbuf[3][3];
    unsigned int ubuf[3][3];
    float        wv[NCO][9];

#define ISSUE_STEP(S)                                                          \
    {                                                                          \
        const TIN* rp = base + (size_t)((S) >> 2) * HIN * WSIN                 \
                             + (size_t)((S) & 3) * WSIN;                       \
        if constexpr (IN_U8) {                                                 \
            ubuf[(S) % 3][0] = *(const unsigned int*)&rp[4 * u0];              \
            ubuf[(S) % 3][1] = *(const unsigned int*)&rp[4 * u1];              \
            ubuf[(S) % 3][2] = *(const unsigned int*)&rp[4 * u2];              \
        } else {                                                               \
            fbuf[(S) % 3][0] = *(const float4*)&rp[4 * u0];                    \
            fbuf[(S) % 3][1] = *(const float4*)&rp[4 * u1];                    \
            fbuf[(S) % 3][2] = *(const float4*)&rp[4 * u2];                    \
        }                                                                      \
    }

    ISSUE_STEP(0);
    ISSUE_STEP(1);

#pragma unroll
    for (int s = 0; s < STEPS; ++s) {
        const int c  = s >> 2;
        const int rr = s & 3;

        if (s + 2 < STEPS) ISSUE_STEP(s + 2);

        if (rr == 0) {
#pragma unroll
            for (int j = 0; j < NCO; ++j)
#pragma unroll
                for (int k = 0; k < 9; ++k)
                    wv[j][k] = lw[((NCO * cog + j) * CIN + c) * 9 + k];
        }

        float row[12];
        if constexpr (IN_U8) {
#pragma unroll
            for (int k = 0; k < 3; ++k) {
                const unsigned int d = ubuf[s % 3][k];
#pragma unroll
                for (int b = 0; b < 4; ++b)
                    row[4 * k + b] = (float)((d >> (8 * b)) & 0xffu) * step_in;
            }
        } else {
            const float* rv = (const float*)fbuf[s % 3];
#pragma unroll
            for (int i = 0; i < 12; ++i) row[i] = rv[i];
        }

        if (rr < 3) {
#pragma unroll
            for (int j = 0; j < NCO; ++j)
#pragma unroll
                for (int kc = 0; kc < 3; ++kc)
#pragma unroll
                    for (int xx = 0; xx < 8; ++xx)
                        acc[j][xx] = fmaf(row[xx + kc], wv[j][rr * 3 + kc], acc[j][xx]);
        }
        if (rr >= 1) {
#pragma unroll
            for (int j = 0; j < NCO; ++j)
#pragma unroll
                for (int kc = 0; kc < 3; ++kc)
#pragma unroll
                    for (int xx = 0; xx < 8; ++xx)
                        acc[j][8 + xx] = fmaf(row[xx + kc], wv[j][(rr - 1) * 3 + kc], acc[j][8 + xx]);
        }
    }
#undef ISSUE_STEP

#pragma unroll
    for (int j = 0; j < NCO; ++j) {
        const int co = NCO * cog + j;
        const float bias = HAS_BIAS ? lb[co] : 0.0f;
        unsigned int pck = 0;
#pragma unroll
        for (int t = 0; t < 4; ++t) {
            float m = fmaxf(fmaxf(acc[j][2 * t], acc[j][2 * t + 1]),
                            fmaxf(acc[j][8 + 2 * t], acc[j][8 + 2 * t + 1]));
            float v = fmaxf(m + bias, 0.0f);
            float q = rintf(v / step);
            q = fminf(fmaxf(q, 0.0f), 15.0f);
            const unsigned int qi = (4 * xg + t < WPOOL) ? (unsigned int)q : 0u;
            pck |= qi << (8 * t);
        }
        *(unsigned int*)&out[(((size_t)n * COUT + co) * HPOOL + r) * WSOUT + 4 * xg] = pck;
    }
}

__device__ __forceinline__ float wave_max(float v) {
#pragma unroll
    for (int off = 32; off > 0; off >>= 1)
        v = fmaxf(v, __shfl_down(v, off));
    return v;
}

// ---------------------------------------------------------------------------
// Mega tail: stage3 + stage4 + stage5 + fc1 + fc2 + fc3, one block per image,
// 1024 threads (grid is 1 block/CU, so threads are the only TLP lever).
// Stage-3 input slab stored as u8 levels (18.2 KB), dequantized on read
// (exact). A3/O4 stay f32. ~66 KB LDS.
// ---------------------------------------------------------------------------
__global__ __launch_bounds__(1024)
void tail_mega(const unsigned char* __restrict__ in2,  // u8 [256][12][38][40]
               const float* __restrict__ w3, const float* __restrict__ b3,
               const float* __restrict__ w4, const float* __restrict__ b4,
               const float* __restrict__ w5, const float* __restrict__ b5,
               const float* __restrict__ fw1, const float* __restrict__ fb1,
               const float* __restrict__ fw2, const float* __restrict__ fb2,
               const float* __restrict__ fw3,
               const float* __restrict__ s2, const float* __restrict__ s3,
               const float* __restrict__ s4, const float* __restrict__ s5,
               const float* __restrict__ s6, const float* __restrict__ s7,
               float* __restrict__ out)
{
    __shared__ unsigned int SLu[4560];   // 18240 B u8 slab
    __shared__ float A3[5832];
    __shared__ float W3q[1944], W4q[2916], W5q[2916];
    __shared__ float B3q[18], B4q[18], B5q[18];
    __shared__ float O4[1152];
    __shared__ float A5[162], A6[120], A7[84];
    __shared__ float sm[16][6];
    __shared__ float scales[6];

    const int n    = blockIdx.x;
    const int tid  = threadIdx.x;
    const int wid  = tid >> 6;
    const int lane = tid & 63;

    // ---- phase 0: slab + weights to LDS, scales via wave+LDS reduction ----
    {
        const uint4* src = (const uint4*)(in2 + (size_t)n * 18240);
        uint4* dst = (uint4*)SLu;
        for (int i = tid; i < 1140; i += 1024) dst[i] = src[i];
    }
    float m3 = 0.f, m4 = 0.f, m5 = 0.f, g1 = 0.f, g2 = 0.f, g3 = 0.f;
    for (int i = tid; i < 1944; i += 1024) { const float v = w3[i]; W3q[i] = v; m3 = fmaxf(m3, fabsf(v)); }
    for (int i = tid; i < 2916; i += 1024) { const float v = w4[i]; W4q[i] = v; m4 = fmaxf(m4, fabsf(v)); }
    for (int i = tid; i < 2916; i += 1024) { const float v = w5[i]; W5q[i] = v; m5 = fmaxf(m5, fabsf(v)); }
    {
        const float4* f1 = (const float4*)fw1;
        for (int i = tid; i < 4860; i += 1024) {
            const float4 v = f1[i];
            g1 = fmaxf(g1, fmaxf(fmaxf(fabsf(v.x), fabsf(v.y)), fmaxf(fabsf(v.z), fabsf(v.w))));
        }
        const float4* f2 = (const float4*)fw2;
        for (int i = tid; i < 2520; i += 1024) {
            const float4 v = f2[i];
            g2 = fmaxf(g2, fmaxf(fmaxf(fabsf(v.x), fabsf(v.y)), fmaxf(fabsf(v.z), fabsf(v.w))));
        }
        const float4* f3 = (const float4*)fw3;
        for (int i = tid; i < 189; i += 1024) {
            const float4 v = f3[i];
            g3 = fmaxf(g3, fmaxf(fmaxf(fabsf(v.x), fabsf(v.y)), fmaxf(fabsf(v.z), fabsf(v.w))));
        }
    }
    if (tid < 18) { B3q[tid] = b3[tid]; B4q[tid] = b4[tid]; B5q[tid] = b5[tid]; }
    m3 = wave_max(m3); m4 = wave_max(m4); m5 = wave_max(m5);
    g1 = wave_max(g1); g2 = wave_max(g2); g3 = wave_max(g3);
    if (lane == 0) {
        sm[wid][0] = m3; sm[wid][1] = m4; sm[wid][2] = m5;
        sm[wid][3] = g1; sm[wid][4] = g2; sm[wid][5] = g3;
    }
    __syncthreads();
    if (tid < 6) {
        float v = sm[0][tid];
#pragma unroll
        for (int w = 1; w < 16; ++w) v = fmaxf(v, sm[w][tid]);
        scales[tid] = v / 3.0f;
    }
    __syncthreads();
    const float sw3 = scales[0], sw4 = scales[1], sw5 = scales[2];
    const float sf1 = scales[3], sf2 = scales[4], sf3 = scales[5];

    for (int i = tid; i < 1944; i += 1024) { float q = rintf(W3q[i] / sw3); q = fminf(fmaxf(q, -3.f), 3.f); W3q[i] = q * sw3; }
    for (int i = tid; i < 2916; i += 1024) { float q = rintf(W4q[i] / sw4); q = fminf(fmaxf(q, -3.f), 3.f); W4q[i] = q * sw4; }
    for (int i = tid; i < 2916; i += 1024) { float q = rintf(W5q[i] / sw5); q = fminf(fmaxf(q, -3.f), 3.f); W5q[i] = q * sw5; }
    if (tid < 18) {
        const float sb3 = sw3 * (s2[0] / 15.0f); B3q[tid] = rintf(B3q[tid] / sb3) * sb3;
        const float sb4 = sw4 * (s3[0] / 15.0f); B4q[tid] = rintf(B4q[tid] / sb4) * sb4;
        const float sb5 = sw5 * (s4[0] / 15.0f); B5q[tid] = rintf(B5q[tid] / sb5) * sb5;
    }
    __syncthreads();

    // ---- phase 1: stage3 [12,38,38]->[18,18,18]; u8 slab dequant on read ----
    {
        const unsigned char* SLb = (const unsigned char*)SLu;
        const float step2 = s2[0] / 15.0f;
        const float st = s3[0] / 15.0f;
        if (tid < 972) {
            const int r  = tid / 54;
            const int rm = tid - r * 54;
            const int co = rm / 3;
            const int th = rm - co * 3;       // pooled x in [6*th, 6*th+6)

            float acc0[12], acc1[12];
#pragma unroll
            for (int i = 0; i < 12; ++i) { acc0[i] = 0.f; acc1[i] = 0.f; }

            for (int c = 0; c < 12; ++c) {
                float wvv[9];
#pragma unroll
                for (int k = 0; k < 9; ++k) wvv[k] = W3q[(co * 12 + c) * 9 + k];
#pragma unroll
                for (int rr = 0; rr < 4; ++rr) {
                    const int off = (c * 38 + 2 * r + rr) * 40 + 12 * th;
                    float row[16];
#pragma unroll
                    for (int k = 0; k < 4; ++k) {
                        const unsigned int d = *(const unsigned int*)&SLb[off + 4 * k];
#pragma unroll
                        for (int b = 0; b < 4; ++b)
                            row[4 * k + b] = (float)((d >> (8 * b)) & 0xffu) * step2;
                    }
                    if (rr < 3) {
#pragma unroll
                        for (int kc = 0; kc < 3; ++kc)
#pragma unroll
                            for (int xx = 0; xx < 12; ++xx)
                                acc0[xx] = fmaf(row[xx + kc], wvv[rr * 3 + kc], acc0[xx]);
                    }
                    if (rr >= 1) {
#pragma unroll
                        for (int kc = 0; kc < 3; ++kc)
#pragma unroll
                            for (int xx = 0; xx < 12; ++xx)
                                acc1[xx] = fmaf(row[xx + kc], wvv[(rr - 1) * 3 + kc], acc1[xx]);
                    }
                }
            }
            const float bias = B3q[co];
#pragma unroll
            for (int x = 0; x < 6; ++x) {
                float m = fmaxf(fmaxf(acc0[2 * x], acc0[2 * x + 1]),
                                fmaxf(acc1[2 * x], acc1[2 * x + 1]));
                float v = fmaxf(m + bias, 0.0f);
                float q = rintf(v / st);
                q = fminf(fmaxf(q, 0.0f), 15.0f);
                A3[(co * 18 + r) * 18 + 6 * th + x] = q * st;
            }
        }
    }
    __syncthreads();

    // ---- phase 2: stage4 [18,18,18]->[18,8,8] ----
    {
        const float st = s4[0] / 15.0f;
        for (int o = tid; o < 1152; o += 1024) {
            const int co = o >> 6;
            const int r  = (o >> 3) & 7;
            const int x  = o & 7;
            float a00 = 0.f, a01 = 0.f, a10 = 0.f, a11 = 0.f;
            for (int c = 0; c < 18; ++c) {
                float win[4][4];
#pragma unroll
                for (int rr = 0; rr < 4; ++rr) {
                    const int base = c * 324 + (2 * r + rr) * 18 + 2 * x;
                    *(float2*)&win[rr][0] = *(const float2*)&A3[base];
                    *(float2*)&win[rr][2] = *(const float2*)&A3[base + 2];
                }
                const float* wp = &W4q[(co * 18 + c) * 9];
#pragma unroll
                for (int kr = 0; kr < 3; ++kr)
#pragma unroll
                    for (int kc = 0; kc < 3; ++kc) {
                        const float wvv = wp[kr * 3 + kc];
                        a00 = fmaf(win[kr    ][kc    ], wvv, a00);
                        a01 = fmaf(win[kr    ][kc + 1], wvv, a01);
                        a10 = fmaf(win[kr + 1][kc    ], wvv, a10);
                        a11 = fmaf(win[kr + 1][kc + 1], wvv, a11);
                    }
            }
            float m = fmaxf(fmaxf(a00, a01), fmaxf(a10, a11));
            float v = fmaxf(m + B4q[co], 0.0f);
            float q = rintf(v / st);
            q = fminf(fmaxf(q, 0.0f), 15.0f);
            O4[o] = q * st;                  // layout (co, r, x)
        }
    }
    __syncthreads();

    // ---- phase 3: stage5 [18,8,8]->[18,3,3] = A5[162] ----
    {
        const float st = s5[0] / 15.0f;
        if (tid < 162) {
            const int co  = tid / 9;
            const int rem = tid - co * 9;
            const int r   = rem / 3;
            const int x   = rem - r * 3;
            float a00 = 0.f, a01 = 0.f, a10 = 0.f, a11 = 0.f;
            for (int c = 0; c < 18; ++c) {
                float win[4][4];
#pragma unroll
                for (int rr = 0; rr < 4; ++rr) {
                    const int base = c * 64 + (2 * r + rr) * 8 + 2 * x;
                    *(float2*)&win[rr][0] = *(const float2*)&O4[base];
                    *(float2*)&win[rr][2] = *(const float2*)&O4[base + 2];
                }
                const float* wp = &W5q[(co * 18 + c) * 9];
#pragma unroll
                for (int kr = 0; kr < 3; ++kr)
#pragma unroll
                    for (int kc = 0; kc < 3; ++kc) {
                        const float wvv = wp[kr * 3 + kc];
                        a00 = fmaf(win[kr    ][kc    ], wvv, a00);
                        a01 = fmaf(win[kr    ][kc + 1], wvv, a01);
                        a10 = fmaf(win[kr + 1][kc    ], wvv, a10);
                        a11 = fmaf(win[kr + 1][kc + 1], wvv, a11);
                    }
            }
            float m = fmaxf(fmaxf(a00, a01), fmaxf(a10, a11));
            float v = fmaxf(m + B5q[co], 0.0f);
            float q = rintf(v / st);
            q = fminf(fmaxf(q, 0.0f), 15.0f);
            A5[tid] = q * st;                // (co, r, x) = reference reshape order
        }
    }
    __syncthreads();

    // ---- fc1: [162]->[120], on-the-fly weight quant ----
    if (tid < 120) {
        float acc = 0.f;
        const float* wr = fw1 + (size_t)tid * 162;
#pragma unroll 6
        for (int k = 0; k < 162; ++k) {
            float q = rintf(wr[k] / sf1);
            q = fminf(fmaxf(q, -3.f), 3.f);
            acc = fmaf(A5[k], q * sf1, acc);
        }
        const float sb = sf1 * (s5[0] / 15.0f);
        acc += rintf(fb1[tid] / sb) * sb;
        const float st = s6[0] / 15.0f;
        float q = rintf(fmaxf(acc, 0.0f) / st);
        q = fminf(fmaxf(q, 0.0f), 15.0f);
        A6[tid] = q * st;
    }
    __syncthreads();

    // ---- fc2: [120]->[84] ----
    if (tid < 84) {
        float acc = 0.f;
        const float* wr = fw2 + (size_t)tid * 120;
#pragma unroll 6
        for (int k = 0; k < 120; ++k) {
            float q = rintf(wr[k] / sf2);
            q = fminf(fmaxf(q, -3.f), 3.f);
            acc = fmaf(A6[k], q * sf2, acc);
        }
        const float sb = sf2 * (s6[0] / 15.0f);
        acc += rintf(fb2[tid] / sb) * sb;
        const float st = s7[0] / 15.0f;
        float q = rintf(fmaxf(acc, 0.0f) / st);
        q = fminf(fmaxf(q, 0.0f), 15.0f);
        A7[tid] = q * st;
    }
    __syncthreads();

    // ---- fc3: [84]->[9] (no bias, no quant) ----
    if (tid < 9) {
        float acc = 0.f;
        const float* wr = fw3 + (size_t)tid * 84;
#pragma unroll 6
        for (int k = 0; k < 84; ++k) {
            float q = rintf(wr[k] / sf3);
            q = fminf(fmaxf(q, -3.f), 3.f);
            acc = fmaf(A7[k], q * sf3, acc);
        }
        out[(size_t)n * 9 + tid] = acc;
    }
}

// ---------------------------------------------------------------------------
extern "C" void kernel_launch(void* const* d_in, const int* in_sizes, int n_in,
                              void* d_out, int out_size, void* d_ws, size_t ws_size,
                              hipStream_t stream)
{
    const float* x   = (const float*)d_in[0];
    const float* w1  = (const float*)d_in[1];
    const float* w2  = (const float*)d_in[2];
    const float* b2  = (const float*)d_in[3];
    const float* w3  = (const float*)d_in[4];
    const float* b3  = (const float*)d_in[5];
    const float* w4  = (const float*)d_in[6];
    const float* b4  = (const float*)d_in[7];
    const float* w5  = (const float*)d_in[8];
    const float* b5  = (const float*)d_in[9];
    const float* fw1 = (const float*)d_in[10];
    const float* fb1 = (const float*)d_in[11];
    const float* fw2 = (const float*)d_in[12];
    const float* fb2 = (const float*)d_in[13];
    const float* fw3 = (const float*)d_in[14];
    const float* s1  = (const float*)d_in[15];
    const float* s2  = (const float*)d_in[16];
    const float* s3  = (const float*)d_in[17];
    const float* s4  = (const float*)d_in[18];
    const float* s5  = (const float*)d_in[19];
    const float* s6  = (const float*)d_in[20];
    const float* s7  = (const float*)d_in[21];

    unsigned char* wsb = (unsigned char*)d_ws;
    float* out = (float*)d_out;

    // stage 1: f32 in -> u8 levels out [256][6][79][80]
    conv_stage<3, 6, 2, 160, 160, 79, 79, 80, 20, 4, 256, false, false>
        <<<dim3(20, 256), 256, 0, stream>>>(x, w1, nullptr, nullptr, s1,
                                            wsb + OFF_OUT1B);

    // stage 2: u8 in -> u8 levels out [256][12][38][40]
    conv_stage<6, 12, 2, 79, 80, 38, 38, 40, 10, 4, 256, true, true>
        <<<dim3(10, 256), 256, 0, stream>>>(wsb + OFF_OUT1B, w2, b2, s1, s2,
                                            wsb + OFF_OUT2B);

    // mega tail: stage3+4+5+fc1+fc2+fc3, one 1024-thread block per image
    tail_mega<<<256, 1024, 0, stream>>>(wsb + OFF_OUT2B,
                                        w3, b3, w4, b4, w5, b5,
                                        fw1, fb1, fw2, fb2, fw3,
                                        s2, s3, s4, s5, s6, s7, out);
}